// Round 10
// baseline (325.940 us; speedup 1.0000x reference)
//
#include <hip/hip_runtime.h>
#include <cstdint>
#include <cstddef>

// ============================================================================
// CellSetAttentionNetwork: X[8,2048,512] fp32, single-head attention D=H=512.
// R16: fused attention. Pipeline: cvt -> QKV gemm -> attn_k (QK^T + exp +
// rowsum + PV fused, flash-style but max-free) -> fused out-proj+res+LN.
// Rationale: 10 rounds show the GEMM engine pinned at ~450TF by sync
// structure (all schedule tweaks null; both work-removal moves won). attn_k
// deletes the S buffer (128MB HBM round-trip), rsum atomics, and 1.3GB of
// scores/PV staging, replacing them with 1GB of L2-resident K/V streaming.
//   - 256 blocks (QBLK=64 x 8 batch) = 1/CU, one round. m204 XCD swizzle
//     maps batch==XCD: K_z+V_z = 4MB resident in that XCD's L2.
//   - Q in registers (128 VGPR: 2x16 bf16x8 frags), ctx acc[4][8] f32x4
//     (128 VGPR); ~320 total, legal on gfx950 (no spill through 450, m08).
//   - LDS 136KB: Ks[64][512] + Vs[512][64] + Es[64][64], all R12-proven
//     both-sides chunk swizzle (slot s of row r = logical chunk s^(r&7);
//     gld16 writes linearly so the per-lane GLOBAL chunk is pre-swizzled).
//   - per kv-tile (64 kv, 32 tiles): stage K+V (32 gld16/wave) ->
//     vmcnt(16) [K done, V in flight] -> bar -> QK^T (16 ks, qf regs x Ks)
//     -> exp+psum+Es write -> lgkmcnt(0)+vmcnt(0) -> bar -> PV (Es x Vs,
//     2 ks x 8 ht x 4 mt) -> bar.
//   - rowsum: per-lane psum accumulated across tiles; one shfl+LDS reduce
//     at the end; ctx = acc/rowsum (max-free softmax, proven numerics).
// QKV gemm (R6/R7 engine + XCD swizzle) and gemmf_k (R13 fused out-proj+
// bo+residual+LayerNorm) kept verbatim.
//
// ws layout (byte offsets):
//   [0, 16M)      Xb  [16384][512] bf16
//   [64M, +2M)    Wt  [2048][512] bf16 (Wq^T,Wk^T,Wv^T,Wo^T stacked)
//   [66M, +16M)   q   [16384][512] bf16; reused as ctx after attn
//   [82M, +16M)   k   [16384][512] bf16
//   [98M, +16M)   vT  [8][512][2048] bf16
// ============================================================================

typedef __bf16 bf16x8 __attribute__((ext_vector_type(8)));
typedef float  f32x4  __attribute__((ext_vector_type(4)));

__device__ __forceinline__ uint16_t f2bf(float f) {
  union { float f; uint32_t u; } v; v.f = f;
  uint32_t r = v.u + 0x7FFFu + ((v.u >> 16) & 1u);   // RNE
  return (uint16_t)(r >> 16);
}

__device__ __forceinline__ void gld16(const uint16_t* g, uint16_t* l) {
  // async global->LDS, 16B per lane; LDS dest = wave-uniform base + lane*16
  __builtin_amdgcn_global_load_lds(
      (__attribute__((address_space(1))) void*)(g),
      (__attribute__((address_space(3))) void*)(l), 16, 0, 0);
}

// ============================================================================
// attn_k: fused QK^T+softmax(max-free)+PV. 256 threads, 4 waves.
// Block = 64 q-rows of batch z. ctx[q][h] = sum_kv E(q,kv) vT[h][kv] / rowsum.
// ============================================================================
__global__ __launch_bounds__(256, 1) void attn_k(
    const uint16_t* __restrict__ qg, const uint16_t* __restrict__ kg,
    const uint16_t* __restrict__ vTg, uint16_t* __restrict__ ctx,
    float scale) {
  __shared__ alignas(16) uint16_t Ks[64 * 512];   // 64 KB, [kv][d] swizzled
  __shared__ alignas(16) uint16_t Vs[512 * 64];   // 64 KB, [h][kv] swizzled
  __shared__ alignas(16) uint16_t Es[64 * 64];    //  8 KB, [q][kv] swizzled
  __shared__ float rs[64][2];

  const int tid = threadIdx.x;
  const int w = tid >> 6, lane = tid & 63;
  const int wm = w >> 1, wn = w & 1;          // QK^T 2x2 wave grid
  const int lr = lane & 15, q4 = lane >> 4;
  const int lr7 = lr & 7;
  const int l3 = lane >> 3, l7 = lane & 7;

  // XCD swizzle (m204, nwg=256): batch z == XCD; K_z+V_z L2-resident.
  const int hw = blockIdx.x + 32 * blockIdx.y;
  const int lg = (hw & 7) * 32 + (hw >> 3);
  const int bx = lg & 31, z = lg >> 5;
  const int q0 = bx * 64;

  const uint16_t* qb = qg + ((size_t)z * 2048 + q0) * 512;
  const uint16_t* kb = kg + (size_t)z * 2048 * 512;
  const uint16_t* vb = vTg + (size_t)z * 512 * 2048;

  // Q fragments in registers: rows wm*32+mt*16+lr, d-chunk ks*32+q4*8
  bf16x8 qf[2][16];
#pragma unroll
  for (int mt = 0; mt < 2; mt++)
#pragma unroll
    for (int ks = 0; ks < 16; ks++)
      qf[mt][ks] = *(const bf16x8*)&qb[(size_t)(wm * 32 + mt * 16 + lr) * 512 +
                                       ks * 32 + q4 * 8];
  // drain Q loads so loop's counted vmcnt sees only gld16s (loads cannot
  // sink past a "memory"-clobber asm)
  asm volatile("s_waitcnt vmcnt(0)" ::: "memory");

  f32x4 acc[4][8];                 // ctx: rows mt*16.., cols w*128+ht*16..
#pragma unroll
  for (int mt = 0; mt < 4; mt++)
#pragma unroll
    for (int ht = 0; ht < 8; ht++) acc[mt][ht] = (f32x4){0.f, 0.f, 0.f, 0.f};
  float psum[2][4] = {{0.f, 0.f, 0.f, 0.f}, {0.f, 0.f, 0.f, 0.f}};

  for (int kt = 0; kt < 32; ++kt) {
    const int kv0 = kt * 64;
    // ---- stage K rows (16 gld16/wave; 1 row = 1024B = one wave gld16) ----
#pragma unroll
    for (int j = 0; j < 16; j++) {
      const int r = w * 16 + j;
      gld16(kb + (size_t)(kv0 + r) * 512 + (lane ^ (r & 7)) * 8, &Ks[r * 512]);
    }
    // ---- stage V groups (16 gld16/wave; 8 h-rows x 64 kv each) ----
#pragma unroll
    for (int j = 0; j < 16; j++) {
      const int g = w * 16 + j;
      gld16(vb + (size_t)(g * 8 + l3) * 2048 + kv0 + (l7 ^ l3) * 8,
            &Vs[g * 512]);
    }
    asm volatile("s_waitcnt vmcnt(16)" ::: "memory");   // K done, V in flight
    __builtin_amdgcn_s_barrier();

    // ---- QK^T: S[64][64], wave tile 32x32 ----
    f32x4 sacc[2][2];
#pragma unroll
    for (int mt = 0; mt < 2; mt++)
#pragma unroll
      for (int nt = 0; nt < 2; nt++) sacc[mt][nt] = (f32x4){0.f, 0.f, 0.f, 0.f};
#pragma unroll
    for (int ks = 0; ks < 16; ks++) {
      bf16x8 kf[2];
#pragma unroll
      for (int nt = 0; nt < 2; nt++) {
        const int r = wn * 32 + nt * 16 + lr;
        kf[nt] = *(const bf16x8*)&Ks[r * 512 + ((ks * 4 + q4) ^ lr7) * 8];
      }
#pragma unroll
      for (int nt = 0; nt < 2; nt++)
#pragma unroll
        for (int mt = 0; mt < 2; mt++)
          sacc[mt][nt] = __builtin_amdgcn_mfma_f32_16x16x32_bf16(
              qf[mt][ks], kf[nt], sacc[mt][nt], 0, 0, 0);
    }
    // ---- E = exp(s*scale); psum accumulate; write Es (swizzled) ----
#pragma unroll
    for (int mt = 0; mt < 2; mt++)
#pragma unroll
      for (int nt = 0; nt < 2; nt++)
#pragma unroll
        for (int i = 0; i < 4; i++) {
          const float e = __expf(sacc[mt][nt][i] * scale);
          const int r = wm * 32 + mt * 16 + q4 * 4 + i;
          const int c = wn * 32 + nt * 16 + lr;
          Es[r * 64 + (((c >> 3) ^ (r & 7)) * 8) + lr7] = f2bf(e);
          psum[mt][i] += e;
        }
    asm volatile("s_waitcnt lgkmcnt(0)" ::: "memory");  // Es writes drained
    asm volatile("s_waitcnt vmcnt(0)" ::: "memory");    // V landed
    __builtin_amdgcn_s_barrier();

    // ---- PV: ctx[64][512] += E[64][64] * V; wave owns cols w*128..+128 ----
#pragma unroll
    for (int ks = 0; ks < 2; ks++) {
      bf16x8 ef[4];
#pragma unroll
      for (int mt = 0; mt < 4; mt++)
        ef[mt] = *(const bf16x8*)&Es[(mt * 16 + lr) * 64 +
                                     ((ks * 4 + q4) ^ lr7) * 8];
#pragma unroll
      for (int ht = 0; ht < 8; ht++) {
        const int h = w * 128 + ht * 16 + lr;
        const bf16x8 vf =
            *(const bf16x8*)&Vs[h * 64 + ((ks * 4 + q4) ^ lr7) * 8];
#pragma unroll
        for (int mt = 0; mt < 4; mt++)
          acc[mt][ht] = __builtin_amdgcn_mfma_f32_16x16x32_bf16(
              ef[mt], vf, acc[mt][ht], 0, 0, 0);
      }
    }
    __builtin_amdgcn_s_barrier();   // PV reads done; Ks/Vs free for next tile
  }

  // ---- rowsum finalize: shfl over lr, cross-wn via LDS ----
#pragma unroll
  for (int mt = 0; mt < 2; mt++)
#pragma unroll
    for (int i = 0; i < 4; i++) {
      float p = psum[mt][i];
      p += __shfl_xor(p, 1); p += __shfl_xor(p, 2);
      p += __shfl_xor(p, 4); p += __shfl_xor(p, 8);
      if (lr == 0) rs[wm * 32 + mt * 16 + q4 * 4 + i][wn] = p;
    }
  __syncthreads();

  // ---- ctx = acc / rowsum ----
#pragma unroll
  for (int mt = 0; mt < 4; mt++)
#pragma unroll
    for (int i = 0; i < 4; i++) {
      const int r = mt * 16 + q4 * 4 + i;
      const float inv = 1.0f / (rs[r][0] + rs[r][1]);
#pragma unroll
      for (int ht = 0; ht < 8; ht++) {
        const int col = w * 128 + ht * 16 + lr;
        ctx[((size_t)z * 2048 + q0 + r) * 512 + col] =
            f2bf(acc[mt][ht][i] * inv);
      }
    }
}

// ============================================================================
// QKV gemm (R6/R7 engine + XCD swizzle, R15-proven). 256 threads, 4 waves
// 2x2, 128^2 tile, BK=32, 3 LDS buffers, depth-2, one barrier/iter.
// out q, k normal [M][512]; v transposed vT[b][h][t]; +bias.
// ============================================================================
template <int BM, int BN>
__global__ __launch_bounds__(256, 2) void gemm_k(
    const uint16_t* __restrict__ A, const uint16_t* __restrict__ Bt,
    uint16_t* __restrict__ OutQ, uint16_t* __restrict__ OutK,
    uint16_t* __restrict__ OutVT, int K, int lda, int ldb,
    const float* __restrict__ b0, const float* __restrict__ b1,
    const float* __restrict__ b2) {
  constexpr int MT = BM / 32;
  constexpr int NT = BN / 32;
  constexpr int AI = BM / 64;
  constexpr int BI = BN / 64;
  constexpr int PW = AI + BI;
  __shared__ alignas(16) uint16_t As[3][BM * 32];
  __shared__ alignas(16) uint16_t Bs[3][BN * 32];

  const int tid = threadIdx.x;
  const int w = tid >> 6, lane = tid & 63;
  const int wm = w >> 1, wn = w & 1;

  const int gx = gridDim.x, gy = gridDim.y;
  const int nwg = gx * gy;
  const int hw = blockIdx.x + gx * blockIdx.y;
  const int lg = (hw & 7) * (nwg >> 3) + (hw >> 3);
  const int bx = lg % gx, by = lg / gx;

  const int m0 = by * BM, n0 = bx * BN;

  const int kc = (((lane & 3) ^ ((lane >> 2) & 3) ^ (lane >> 4)) * 8);
  const int rbA = w * (BM / 4);
  const int rbB = w * (BN / 4);
  const uint16_t* gA = A + (size_t)(m0 + rbA + (lane >> 2)) * lda + kc;
  const uint16_t* gB = Bt + (size_t)(n0 + rbB + (lane >> 2)) * ldb + kc;

  f32x4 acc[MT][NT];
#pragma unroll
  for (int i = 0; i < MT; i++)
#pragma unroll
    for (int j = 0; j < NT; j++) acc[i][j] = (f32x4){0.f, 0.f, 0.f, 0.f};

  const int lr = lane & 15, q4 = lane >> 4;
  const int swz = (((lane >> 4) ^ (lr & 3) ^ (lr >> 2)) * 8);
  const int iters = K >> 5;

  auto stage = [&](int t, int buf) {
    const int k0 = t * 32;
#pragma unroll
    for (int j = 0; j < AI; j++)
      gld16(gA + k0 + (size_t)(j * 16) * lda, &As[buf][(rbA + j * 16) * 32]);
#pragma unroll
    for (int j = 0; j < BI; j++)
      gld16(gB + k0 + (size_t)(j * 16) * ldb, &Bs[buf][(rbB + j * 16) * 32]);
  };

  auto compute = [&](int buf) {
    bf16x8 af[MT], bfr[NT];
#pragma unroll
    for (int t = 0; t < MT; t++)
      af[t] = *(const bf16x8*)&As[buf][(wm * (BM / 2) + t * 16 + lr) * 32 + swz];
#pragma unroll
    for (int t = 0; t < NT; t++)
      bfr[t] = *(const bf16x8*)&Bs[buf][(wn * (BN / 2) + t * 16 + lr) * 32 + swz];
#pragma unroll
    for (int nt = 0; nt < NT; nt++)
#pragma unroll
      for (int mt = 0; mt < MT; mt++)
        acc[mt][nt] = __builtin_amdgcn_mfma_f32_16x16x32_bf16(
            af[mt], bfr[nt], acc[mt][nt], 0, 0, 0);
  };

  stage(0, 0);
  stage(1, 1);
  int buf = 0;
  for (int i = 0; i < iters - 1; ++i) {
    asm volatile("s_waitcnt vmcnt(%0)" ::"i"(PW) : "memory");
    __builtin_amdgcn_s_barrier();
    if (i + 2 < iters) stage(i + 2, (buf + 2 >= 3) ? buf - 1 : buf + 2);
    compute(buf);
    buf = (buf == 2) ? 0 : buf + 1;
  }
  asm volatile("s_waitcnt vmcnt(0)" ::: "memory");
  __builtin_amdgcn_s_barrier();
  compute(buf);

#pragma unroll
  for (int mt = 0; mt < MT; mt++) {
#pragma unroll
    for (int nt = 0; nt < NT; nt++) {
#pragma unroll
      for (int i = 0; i < 4; i++) {
        const int row = m0 + wm * (BM / 2) + mt * 16 + q4 * 4 + i;
        const int col = n0 + wn * (BN / 2) + nt * 16 + lr;
        const float v = acc[mt][nt][i];
        const int which = col >> 9, c = col & 511;
        if (which == 0) {
          OutQ[(size_t)row * 512 + c] = f2bf(v + b0[c]);
        } else if (which == 1) {
          OutK[(size_t)row * 512 + c] = f2bf(v + b1[c]);
        } else {  // v -> transposed vT[b][h][t]
          OutVT[(size_t)(row >> 11) * (512 * 2048) + (size_t)c * 2048 +
                (row & 2047)] = f2bf(v + b2[c]);
        }
      }
    }
  }
}

// ============================================================================
// gemmf_k (R13-proven): out-proj + b0 + Xres residual + LayerNorm,
// 512 threads, BM=64 x BN=512 (block owns full rows), 1x8 wave grid.
// ============================================================================
template <int BM, int BN, int WM, int WN>
__global__ __launch_bounds__(512, 4) void gemmf_k(
    const uint16_t* __restrict__ A, const uint16_t* __restrict__ Bt,
    void* __restrict__ OutA, int K, int lda, int ldb,
    const float* __restrict__ b0, const float* __restrict__ b1,
    const float* __restrict__ b2, const float* __restrict__ Xres) {
  constexpr int MT = (BM / WM) / 16;
  constexpr int NT = (BN / WN) / 16;
  static_assert(MT == 4 && NT == 4, "wave tile must be 64x64");
  constexpr int AI = (BM >= 128) ? BM / 128 : 1;
  constexpr int BI = BN / 128;
  constexpr int PW = AI + BI;
  __shared__ alignas(16) uint16_t As[3][BM * 32];
  __shared__ alignas(16) uint16_t Bs[3][BN * 32];

  const int tid = threadIdx.x;
  const int w = tid >> 6, lane = tid & 63;
  const int wm = w / WN, wn = w % WN;

  const int gx = gridDim.x, gy = gridDim.y;
  const int nwg = gx * gy;
  const int hw = blockIdx.x + gx * blockIdx.y;
  const int lg = (hw & 7) * (nwg >> 3) + (hw >> 3);
  const int bx = lg % gx, by = lg / gx;

  const int m0 = by * BM, n0 = bx * BN;

  const int kc = (((lane & 3) ^ ((lane >> 2) & 3) ^ (lane >> 4)) * 8);
  const int rbA = (BM >= 128) ? w * (BM / 8) : (w & 3) * 16;
  const int rbB = w * (BN / 8);
  const uint16_t* gA = A + (size_t)(m0 + rbA + (lane >> 2)) * lda + kc;
  const uint16_t* gB = Bt + (size_t)(n0 + rbB + (lane >> 2)) * ldb + kc;

  f32x4 acc[MT][NT];
#pragma unroll
  for (int i = 0; i < MT; i++)
#pragma unroll
    for (int j = 0; j < NT; j++) acc[i][j] = (f32x4){0.f, 0.f, 0.f, 0.f};

  const int lr = lane & 15, q4 = lane >> 4;
  const int swz = (((lane >> 4) ^ (lr & 3) ^ (lr >> 2)) * 8);
  const int iters = K >> 5;

  auto stage = [&](int t, int buf) {
    const int k0 = t * 32;
#pragma unroll
    for (int j = 0; j < AI; j++)
      gld16(gA + k0 + (size_t)(j * 16) * lda, &As[buf][(rbA + j * 16) * 32]);
#pragma unroll
    for (int j = 0; j < BI; j++)
      gld16(gB + k0 + (size_t)(j * 16) * ldb, &Bs[buf][(rbB + j * 16) * 32]);
  };

  auto compute = [&](int buf) {
    bf16x8 af[MT], bfr[NT];
#pragma unroll
    for (int t = 0; t < MT; t++)
      af[t] = *(const bf16x8*)&As[buf][(wm * (BM / WM) + t * 16 + lr) * 32 + swz];
#pragma unroll
    for (int t = 0; t < NT; t++)
      bfr[t] = *(const bf16x8*)&Bs[buf][(wn * (BN / WN) + t * 16 + lr) * 32 + swz];
#pragma unroll
    for (int nt = 0; nt < NT; nt++)
#pragma unroll
      for (int mt = 0; mt < MT; mt++)
        acc[mt][nt] = __builtin_amdgcn_mfma_f32_16x16x32_bf16(
            af[mt], bfr[nt], acc[mt][nt], 0, 0, 0);
  };

  stage(0, 0);
  stage(1, 1);
  int buf = 0;
  for (int i = 0; i < iters - 1; ++i) {
    asm volatile("s_waitcnt vmcnt(%0)" ::"i"(PW) : "memory");
    __builtin_amdgcn_s_barrier();
    if (i + 2 < iters) stage(i + 2, (buf + 2 >= 3) ? buf - 1 : buf + 2);
    compute(buf);
    buf = (buf == 2) ? 0 : buf + 1;
  }
  asm volatile("s_waitcnt vmcnt(0)" ::: "memory");
  __builtin_amdgcn_s_barrier();
  compute(buf);

  __shared__ float redS[8][64];
  __shared__ float redQ[8][64];
  float* Op = (float*)OutA;
  __syncthreads();
#pragma unroll
  for (int mt = 0; mt < MT; mt++) {
#pragma unroll
    for (int i = 0; i < 4; i++) {
      const int rl = mt * 16 + q4 * 4 + i;
      const int row = m0 + rl;
      float ps = 0.f, pq = 0.f;
#pragma unroll
      for (int nt = 0; nt < NT; nt++) {
        const int col = wn * 64 + nt * 16 + lr;
        float v = acc[mt][nt][i] + b0[col] + Xres[(size_t)row * 512 + col];
        acc[mt][nt][i] = v;
        ps += v; pq += v * v;
      }
      ps += __shfl_xor(ps, 1); pq += __shfl_xor(pq, 1);
      ps += __shfl_xor(ps, 2); pq += __shfl_xor(pq, 2);
      ps += __shfl_xor(ps, 4); pq += __shfl_xor(pq, 4);
      ps += __shfl_xor(ps, 8); pq += __shfl_xor(pq, 8);
      if (lr == 0) { redS[w][rl] = ps; redQ[w][rl] = pq; }
    }
  }
  __syncthreads();
#pragma unroll
  for (int mt = 0; mt < MT; mt++) {
#pragma unroll
    for (int i = 0; i < 4; i++) {
      const int rl = mt * 16 + q4 * 4 + i;
      const int row = m0 + rl;
      float s8 = 0.f, q8 = 0.f;
#pragma unroll
      for (int ww = 0; ww < 8; ww++) { s8 += redS[ww][rl]; q8 += redQ[ww][rl]; }
      const float mean = s8 * (1.f / 512.f);
      const float var = q8 * (1.f / 512.f) - mean * mean;
      const float rstd = rsqrtf(var + 1e-5f);
#pragma unroll
      for (int nt = 0; nt < NT; nt++) {
        const int col = wn * 64 + nt * 16 + lr;
        Op[(size_t)row * 512 + col] =
            (acc[mt][nt][i] - mean) * rstd * b1[col] + b2[col];
      }
    }
  }
}

// Fused conversions: X fp32->bf16 (8.39M elems, 4/thread), Wt transpose.
__global__ __launch_bounds__(256) void cvt_all_k(
    const float* __restrict__ X, uint16_t* __restrict__ Xb,
    const float* __restrict__ Wq, const float* __restrict__ Wk,
    const float* __restrict__ Wv, const float* __restrict__ Wo,
    uint16_t* __restrict__ Wt) {
  const int i = blockIdx.x * 256 + threadIdx.x;   // 0..2097151
  const float4 f = ((const float4*)X)[i];
  uint32_t lo = (uint32_t)f2bf(f.x) | ((uint32_t)f2bf(f.y) << 16);
  uint32_t hi = (uint32_t)f2bf(f.z) | ((uint32_t)f2bf(f.w) << 16);
  ((uint2*)Xb)[i] = make_uint2(lo, hi);
  if (i < 2048 * 512) {   // Wt[n][k] = W[k][n&511]
    const int n = i >> 9, kk = i & 511;
    const int which = n >> 9, c = n & 511;
    const float* W =
        (which == 0) ? Wq : (which == 1) ? Wk : (which == 2) ? Wv : Wo;
    Wt[i] = f2bf(W[kk * 512 + c]);
  }
}

extern "C" void kernel_launch(void* const* d_in, const int* in_sizes, int n_in,
                              void* d_out, int out_size, void* d_ws,
                              size_t ws_size, hipStream_t stream) {
  const float* X     = (const float*)d_in[0];
  const float* Wq    = (const float*)d_in[1];
  const float* bq    = (const float*)d_in[2];
  const float* Wk    = (const float*)d_in[3];
  const float* bk    = (const float*)d_in[4];
  const float* Wv    = (const float*)d_in[5];
  const float* bv    = (const float*)d_in[6];
  const float* Wo    = (const float*)d_in[7];
  const float* bo    = (const float*)d_in[8];
  const float* gamma = (const float*)d_in[9];
  const float* beta  = (const float*)d_in[10];
  float* out = (float*)d_out;

  char* ws = (char*)d_ws;
  uint16_t* Xb   = (uint16_t*)(ws);                 // [0, 16M)
  uint16_t* Wt   = (uint16_t*)(ws + 67108864);      // [64M, 66M)
  uint16_t* q    = (uint16_t*)(ws + 69206016);      // [66M, 82M), later ctx
  uint16_t* kb   = (uint16_t*)(ws + 85983232);      // [82M, 98M)
  uint16_t* vT   = (uint16_t*)(ws + 102760448);     // [98M, 114M)
  uint16_t* ctx  = q;                               // overlay: q dead after attn? no - q read by attn, ctx written after... see below

  // NOTE: attn_k reads q while writing ctx; they must NOT alias. Use Xb
  // region for ctx instead (Xb dead after QKV gemm).
  ctx = Xb;

  cvt_all_k<<<dim3(8192), dim3(256), 0, stream>>>(X, Xb, Wq, Wk, Wv, Wo, Wt);
  // QKV: M=16384, N=1536, K=512, tile 128x128 (1536 blocks)
  gemm_k<128, 128><<<dim3(12, 128), dim3(256), 0, stream>>>(
      Xb, Wt, q, kb, vT, 512, 512, 512, bq, bk, bv);
  // fused attention: 256 blocks (32 q-tiles x 8 batches), 1/CU
  attn_k<<<dim3(32, 8), dim3(256), 0, stream>>>(
      q, kb, vT, ctx, 0.044194173824159216f);
  // fused out-proj + bo + X residual + LayerNorm: M=16384, N=512, K=512
  gemmf_k<64, 512, 1, 8><<<dim3(1, 256), dim3(512), 0, stream>>>(
      ctx, Wt + 1536 * 512, (void*)out, 512, 512, 512, bo, gamma, beta, X);
}